// Round 1
// baseline (607.532 us; speedup 1.0000x reference)
//
#include <hip/hip_runtime.h>
#include <math.h>

#define TEMP 0.07f
#define EPSN 1e-12f

__device__ __forceinline__ float wave_reduce_sum(float v) {
    #pragma unroll
    for (int off = 32; off > 0; off >>= 1)
        v += __shfl_xor(v, off, 64);
    return v;
}

__device__ __forceinline__ float wave_reduce_max(float v) {
    #pragma unroll
    for (int off = 32; off > 0; off >>= 1)
        v = fmaxf(v, __shfl_xor(v, off, 64));
    return v;
}

// ---------------------------------------------------------------------------
// Kernel 1: mean-pool over spatial dims for all four tensors.
// slow: (64,2048,8,7,7) -> 392 floats (98 float4) per (b,c) row
// fast: (64,256,32,7,7) -> 1568 floats (392 float4) per (b,c) row
// One wave per (b,c) row. Output pooled[h][b][c], c<2048 slow, c>=2048 fast.
// ---------------------------------------------------------------------------
__global__ __launch_bounds__(256) void pool_kernel(
    const float* __restrict__ fpv_slow, const float* __restrict__ fpv_fast,
    const float* __restrict__ tpv_slow, const float* __restrict__ tpv_fast,
    float* __restrict__ pool /* [2][64][2304] */)
{
    const int wave = (int)((blockIdx.x * blockDim.x + threadIdx.x) >> 6);
    const int lane = threadIdx.x & 63;

    if (wave < 2 * 131072) {                 // slow tensors: 2^17 rows each
        const int tensor = wave >> 17;
        const int row    = wave & 131071;    // b*2048 + c
        const float* src = tensor ? tpv_slow : fpv_slow;
        const float4* p  = (const float4*)src + (size_t)row * 98;
        float4 a = p[lane];
        float s = a.x + a.y + a.z + a.w;
        if (lane < 34) {
            float4 c4 = p[64 + lane];
            s += c4.x + c4.y + c4.z + c4.w;
        }
        s = wave_reduce_sum(s);
        if (lane == 0) {
            const int b = row >> 11, c = row & 2047;
            pool[tensor * (64 * 2304) + b * 2304 + c] = s * (1.0f / 392.0f);
        }
    } else {                                 // fast tensors: 2^14 rows each
        const int w2     = wave - 2 * 131072;
        const int tensor = w2 >> 14;
        const int row    = w2 & 16383;       // b*256 + c
        const float* src = tensor ? tpv_fast : fpv_fast;
        const float4* p  = (const float4*)src + (size_t)row * 392;
        float s = 0.0f;
        #pragma unroll 2
        for (int i = lane; i < 392; i += 64) {
            float4 a = p[i];
            s += a.x + a.y + a.z + a.w;
        }
        s = wave_reduce_sum(s);
        if (lane == 0) {
            const int b = row >> 8, c = row & 255;
            pool[tensor * (64 * 2304) + b * 2304 + 2048 + c] = s * (1.0f / 1568.0f);
        }
    }
}

// ---------------------------------------------------------------------------
// Kernel 2: per head h, per batch b: xn = l2norm(pooled row);
// y = xn @ W + bias; out = l2norm(y). Grid 128 = 2 heads * 64 rows.
// Wave w covers K-chunk [w*576,(w+1)*576); lane handles cols 4l..4l+3.
// ---------------------------------------------------------------------------
__global__ __launch_bounds__(256) void head_kernel(
    const float* __restrict__ pool,
    const float* __restrict__ W_f, const float* __restrict__ b_f,
    const float* __restrict__ W_t, const float* __restrict__ b_t,
    float* __restrict__ ft /* [2][64][256] */)
{
    __shared__ float xs[2304];
    __shared__ float partial[4][256];
    __shared__ float red[8];

    const int tid  = threadIdx.x;
    const int wv   = tid >> 6, lane = tid & 63;
    const int h    = blockIdx.x >> 6, b = blockIdx.x & 63;
    const float* W    = h ? W_t : W_f;
    const float* bias = h ? b_t : b_f;
    const float* xrow = pool + h * (64 * 2304) + b * 2304;

    float ss = 0.0f;
    #pragma unroll
    for (int r = 0; r < 9; ++r) {
        const int k = tid + r * 256;
        const float v = xrow[k];
        xs[k] = v;
        ss += v * v;
    }
    ss = wave_reduce_sum(ss);
    if (lane == 0) red[wv] = ss;
    __syncthreads();
    const float scale1 = 1.0f / fmaxf(sqrtf(red[0] + red[1] + red[2] + red[3]), EPSN);

    // GEMV chunk: acc[c] = sum_k xs[k] * W[k][c], c = 4*lane..4*lane+3
    float4 acc = make_float4(0.f, 0.f, 0.f, 0.f);
    const int k0 = wv * 576;
    const float4* Wv = (const float4*)W;   // W[k*256 + 4*lane] == Wv[k*64 + lane]
    #pragma unroll 4
    for (int k = 0; k < 576; ++k) {
        const float xk = xs[k0 + k];
        const float4 w4 = Wv[(size_t)(k0 + k) * 64 + lane];
        acc.x += xk * w4.x; acc.y += xk * w4.y;
        acc.z += xk * w4.z; acc.w += xk * w4.w;
    }
    *(float4*)&partial[wv][4 * lane] = acc;
    __syncthreads();

    float y = partial[0][tid] + partial[1][tid] + partial[2][tid] + partial[3][tid];
    y = y * scale1 + bias[tid];

    float ss2 = wave_reduce_sum(y * y);
    if (lane == 0) red[4 + wv] = ss2;
    __syncthreads();
    const float scale2 = 1.0f / fmaxf(sqrtf(red[4] + red[5] + red[6] + red[7]), EPSN);

    ft[h * (64 * 256) + b * 256 + tid] = y * scale2;
}

// ---------------------------------------------------------------------------
// Kernel 3: per row i (64 blocks): sim[j] = f_i . t_j / TEMP;
// pos_i = 0.5*(lv_i.lvlt_i + ln_i.lnlt_i); targets reduced analytically;
// loss_i = m + lse - sum_j targets_ij * sim_ij; atomicAdd(mean contribution).
// ---------------------------------------------------------------------------
__global__ __launch_bounds__(256) void loss_kernel(
    const float* __restrict__ ft,
    const float* __restrict__ lv, const float* __restrict__ lvlt,
    const float* __restrict__ ln, const float* __restrict__ lnlt,
    const int* __restrict__ same_idx,
    float* __restrict__ out)
{
    __shared__ float fs[256];
    __shared__ float sim[64];
    __shared__ float pos_sh;

    const int i   = blockIdx.x;
    const int tid = threadIdx.x, wv = tid >> 6, lane = tid & 63;
    const float* f = ft;
    const float* t = ft + 64 * 256;

    fs[tid] = f[i * 256 + tid];
    if (wv == 3) {
        float s = 0.0f;
        for (int k = lane; k < 97; k += 64)  s += lv[i * 97 + k]  * lvlt[i * 97 + k];
        for (int k = lane; k < 300; k += 64) s += ln[i * 300 + k] * lnlt[i * 300 + k];
        s = wave_reduce_sum(s);
        if (lane == 0) pos_sh = 0.5f * s;
    }
    __syncthreads();

    const float4 a = ((const float4*)fs)[lane];
    for (int jj = 0; jj < 16; ++jj) {
        const int j = wv * 16 + jj;
        const float4 b4 = ((const float4*)(t + j * 256))[lane];
        float d = a.x * b4.x + a.y * b4.y + a.z * b4.z + a.w * b4.w;
        d = wave_reduce_sum(d);
        if (lane == 0) sim[j] = d / TEMP;
    }
    __syncthreads();

    if (wv == 0) {
        const int si = same_idx[i];
        const float pos = pos_sh;
        const float x = sim[lane];
        const float m = wave_reduce_max(x);
        const float e = expf(x - m);
        const float s = wave_reduce_sum(e);
        const float lse = logf(s);
        float w;
        if (si == 2)      w = (lane == i) ? 1.0f : 0.0f;
        else if (si == 0) w = 1.0f / 64.0f;
        else {
            const float neg = (1.0f - pos) * (1.0f / 63.0f);
            w = (lane == i) ? pos : neg;
        }
        const float dotv = wave_reduce_sum(w * x);
        if (lane == 0) atomicAdd(out, (m + lse - dotv) * (1.0f / 64.0f));
    }
}

extern "C" void kernel_launch(void* const* d_in, const int* in_sizes, int n_in,
                              void* d_out, int out_size, void* d_ws, size_t ws_size,
                              hipStream_t stream) {
    const float* fpv_slow   = (const float*)d_in[0];
    const float* fpv_fast   = (const float*)d_in[1];
    const float* tpv_slow   = (const float*)d_in[2];
    const float* tpv_fast   = (const float*)d_in[3];
    const float* labels_v    = (const float*)d_in[4];
    const float* labels_n    = (const float*)d_in[5];
    const float* labels_v_lt = (const float*)d_in[6];
    const float* labels_n_lt = (const float*)d_in[7];
    const int*   same_idx    = (const int*)d_in[8];
    const float* W_fpv = (const float*)d_in[9];
    const float* b_fpv = (const float*)d_in[10];
    const float* W_tpv = (const float*)d_in[11];
    const float* b_tpv = (const float*)d_in[12];

    float* pool = (float*)d_ws;                  // 2*64*2304 floats
    float* ft   = pool + 2 * 64 * 2304;          // 2*64*256 floats
    float* out  = (float*)d_out;

    hipMemsetAsync(d_out, 0, sizeof(float) * out_size, stream);

    // waves: 2*131072 (slow) + 2*16384 (fast) = 294912 -> 73728 blocks of 256
    pool_kernel<<<73728, 256, 0, stream>>>(fpv_slow, fpv_fast, tpv_slow, tpv_fast, pool);
    head_kernel<<<128, 256, 0, stream>>>(pool, W_fpv, b_fpv, W_tpv, b_tpv, ft);
    loss_kernel<<<64, 256, 0, stream>>>(ft, labels_v, labels_v_lt, labels_n, labels_n_lt,
                                        same_idx, out);
}

// Round 2
// 559.148 us; speedup vs baseline: 1.0865x; 1.0865x over previous
//
#include <hip/hip_runtime.h>
#include <math.h>

#define TEMP 0.07f
#define EPSN 1e-12f

__device__ __forceinline__ float wave_reduce_sum(float v) {
    #pragma unroll
    for (int off = 32; off > 0; off >>= 1)
        v += __shfl_xor(v, off, 64);
    return v;
}

__device__ __forceinline__ float wave_reduce_max(float v) {
    #pragma unroll
    for (int off = 32; off > 0; off >>= 1)
        v = fmaxf(v, __shfl_xor(v, off, 64));
    return v;
}

// ---------------------------------------------------------------------------
// Kernel 1: mean-pool. Slow waves handle 4 consecutive rows each (8 loads in
// flight, 4 independent reduce trees, one float4 store). Fast waves handle 1
// row fully unrolled (7 loads in flight).
// slow rows: 131072 per tensor, 98 float4 each -> 32768 waves/tensor
// fast rows: 16384 per tensor, 392 float4 each -> 16384 waves/tensor
// total waves = 2*32768 + 2*16384 = 98304 -> 24576 blocks of 256
// ---------------------------------------------------------------------------
__global__ __launch_bounds__(256) void pool_kernel(
    const float* __restrict__ fpv_slow, const float* __restrict__ fpv_fast,
    const float* __restrict__ tpv_slow, const float* __restrict__ tpv_fast,
    float* __restrict__ pool /* [2][64][2304] */)
{
    const int gw   = (int)((blockIdx.x * blockDim.x + threadIdx.x) >> 6);
    const int lane = threadIdx.x & 63;

    if (gw < 65536) {                         // slow tensors
        const int tensor = gw >> 15;
        const int base   = (gw & 32767) * 4;  // first of 4 rows (b*2048+c)
        const float* src = tensor ? tpv_slow : fpv_slow;
        const float4* p  = (const float4*)src;
        const bool lo    = lane < 34;

        const float4 a0 = p[(size_t)(base + 0) * 98 + lane];
        const float4 a1 = p[(size_t)(base + 1) * 98 + lane];
        const float4 a2 = p[(size_t)(base + 2) * 98 + lane];
        const float4 a3 = p[(size_t)(base + 3) * 98 + lane];
        float s0 = a0.x + a0.y + a0.z + a0.w;
        float s1 = a1.x + a1.y + a1.z + a1.w;
        float s2 = a2.x + a2.y + a2.z + a2.w;
        float s3 = a3.x + a3.y + a3.z + a3.w;
        if (lo) {
            const float4 b0 = p[(size_t)(base + 0) * 98 + 64 + lane];
            const float4 b1 = p[(size_t)(base + 1) * 98 + 64 + lane];
            const float4 b2 = p[(size_t)(base + 2) * 98 + 64 + lane];
            const float4 b3 = p[(size_t)(base + 3) * 98 + 64 + lane];
            s0 += b0.x + b0.y + b0.z + b0.w;
            s1 += b1.x + b1.y + b1.z + b1.w;
            s2 += b2.x + b2.y + b2.z + b2.w;
            s3 += b3.x + b3.y + b3.z + b3.w;
        }
        s0 = wave_reduce_sum(s0);
        s1 = wave_reduce_sum(s1);
        s2 = wave_reduce_sum(s2);
        s3 = wave_reduce_sum(s3);
        if (lane == 0) {
            const int b = base >> 11, c = base & 2047;  // base%4==0, 2048%4==0
            float4 o = make_float4(s0, s1, s2, s3);
            o.x *= (1.0f / 392.0f); o.y *= (1.0f / 392.0f);
            o.z *= (1.0f / 392.0f); o.w *= (1.0f / 392.0f);
            *(float4*)&pool[tensor * (64 * 2304) + b * 2304 + c] = o;
        }
    } else {                                  // fast tensors
        const int w2     = gw - 65536;
        const int tensor = w2 >> 14;
        const int row    = w2 & 16383;        // b*256 + c
        const float* src = tensor ? tpv_fast : fpv_fast;
        const float4* p  = (const float4*)src + (size_t)row * 392;
        const float4 a0 = p[lane];
        const float4 a1 = p[64 + lane];
        const float4 a2 = p[128 + lane];
        const float4 a3 = p[192 + lane];
        const float4 a4 = p[256 + lane];
        const float4 a5 = p[320 + lane];
        float s = (a0.x + a0.y + a0.z + a0.w) + (a1.x + a1.y + a1.z + a1.w)
                + (a2.x + a2.y + a2.z + a2.w) + (a3.x + a3.y + a3.z + a3.w)
                + (a4.x + a4.y + a4.z + a4.w) + (a5.x + a5.y + a5.z + a5.w);
        if (lane < 8) {
            const float4 t = p[384 + lane];
            s += t.x + t.y + t.z + t.w;
        }
        s = wave_reduce_sum(s);
        if (lane == 0) {
            const int b = row >> 8, c = row & 255;
            pool[tensor * (64 * 2304) + b * 2304 + 2048 + c] = s * (1.0f / 1568.0f);
        }
    }
}

// ---------------------------------------------------------------------------
// Kernel 2: split-K GEMV partials on RAW pooled x (l2norm folded out:
// l2norm(x)@W = scale1 * (x@W)). Grid 1152 = (h*64+b)*9 + ks; each block
// handles a K-chunk of 256. Wave wv covers 64 k's; lane -> cols 4l..4l+3.
// gp[idx][c] = sum_{k in chunk} x[k]*W[k][c].
// ---------------------------------------------------------------------------
__global__ __launch_bounds__(256) void gemv_kernel(
    const float* __restrict__ pool,
    const float* __restrict__ W_f, const float* __restrict__ W_t,
    float* __restrict__ gp /* [1152][256] */)
{
    __shared__ float xs[256];
    __shared__ float partial[4][256];

    const int tid = threadIdx.x, wv = tid >> 6, lane = tid & 63;
    const int idx = blockIdx.x;
    const int ks  = idx % 9;
    const int hb  = idx / 9;
    const int h   = hb >> 6, b = hb & 63;
    const float* W = h ? W_t : W_f;

    xs[tid] = pool[h * (64 * 2304) + b * 2304 + ks * 256 + tid];
    __syncthreads();

    float4 acc = make_float4(0.f, 0.f, 0.f, 0.f);
    const float4* Wv = (const float4*)W + (size_t)(ks * 256 + wv * 64) * 64 + lane;
    #pragma unroll 8
    for (int kk = 0; kk < 64; ++kk) {
        const float xk = xs[wv * 64 + kk];
        const float4 w4 = Wv[(size_t)kk * 64];
        acc.x += xk * w4.x; acc.y += xk * w4.y;
        acc.z += xk * w4.z; acc.w += xk * w4.w;
    }
    *(float4*)&partial[wv][4 * lane] = acc;
    __syncthreads();

    gp[(size_t)idx * 256 + tid] =
        partial[0][tid] + partial[1][tid] + partial[2][tid] + partial[3][tid];
}

// ---------------------------------------------------------------------------
// Kernel 3: finalize head. Per (h,b): scale1 from raw x row; y = scale1 *
// sum_ks gp + bias; ft = l2norm(y). Grid 128, block 256.
// ---------------------------------------------------------------------------
__global__ __launch_bounds__(256) void finalize_kernel(
    const float* __restrict__ pool, const float* __restrict__ gp,
    const float* __restrict__ b_f, const float* __restrict__ b_t,
    float* __restrict__ ft /* [2][64][256] */)
{
    __shared__ float red[8];
    const int tid = threadIdx.x, wv = tid >> 6, lane = tid & 63;
    const int h = blockIdx.x >> 6, b = blockIdx.x & 63;

    const float* xrow = pool + h * (64 * 2304) + b * 2304;
    float ss = 0.0f;
    #pragma unroll
    for (int r = 0; r < 9; ++r) {
        const float v = xrow[tid + r * 256];
        ss += v * v;
    }
    ss = wave_reduce_sum(ss);
    if (lane == 0) red[wv] = ss;
    __syncthreads();
    const float scale1 = 1.0f / fmaxf(sqrtf(red[0] + red[1] + red[2] + red[3]), EPSN);

    float y = 0.0f;
    const float* g = gp + (size_t)(h * 64 + b) * 9 * 256;
    #pragma unroll
    for (int ks = 0; ks < 9; ++ks) y += g[ks * 256 + tid];
    const float* bias = h ? b_t : b_f;
    y = y * scale1 + bias[tid];

    const float ss2 = wave_reduce_sum(y * y);
    if (lane == 0) red[4 + wv] = ss2;
    __syncthreads();
    const float scale2 = 1.0f / fmaxf(sqrtf(red[4] + red[5] + red[6] + red[7]), EPSN);

    ft[h * (64 * 256) + b * 256 + tid] = y * scale2;
}

// ---------------------------------------------------------------------------
// Kernel 4: loss (unchanged from R1 — verified correct).
// ---------------------------------------------------------------------------
__global__ __launch_bounds__(256) void loss_kernel(
    const float* __restrict__ ft,
    const float* __restrict__ lv, const float* __restrict__ lvlt,
    const float* __restrict__ ln, const float* __restrict__ lnlt,
    const int* __restrict__ same_idx,
    float* __restrict__ out)
{
    __shared__ float fs[256];
    __shared__ float sim[64];
    __shared__ float pos_sh;

    const int i   = blockIdx.x;
    const int tid = threadIdx.x, wv = tid >> 6, lane = tid & 63;
    const float* f = ft;
    const float* t = ft + 64 * 256;

    fs[tid] = f[i * 256 + tid];
    if (wv == 3) {
        float s = 0.0f;
        for (int k = lane; k < 97; k += 64)  s += lv[i * 97 + k]  * lvlt[i * 97 + k];
        for (int k = lane; k < 300; k += 64) s += ln[i * 300 + k] * lnlt[i * 300 + k];
        s = wave_reduce_sum(s);
        if (lane == 0) pos_sh = 0.5f * s;
    }
    __syncthreads();

    const float4 a = ((const float4*)fs)[lane];
    for (int jj = 0; jj < 16; ++jj) {
        const int j = wv * 16 + jj;
        const float4 b4 = ((const float4*)(t + j * 256))[lane];
        float d = a.x * b4.x + a.y * b4.y + a.z * b4.z + a.w * b4.w;
        d = wave_reduce_sum(d);
        if (lane == 0) sim[j] = d / TEMP;
    }
    __syncthreads();

    if (wv == 0) {
        const int si = same_idx[i];
        const float pos = pos_sh;
        const float x = sim[lane];
        const float m = wave_reduce_max(x);
        const float e = expf(x - m);
        const float s = wave_reduce_sum(e);
        const float lse = logf(s);
        float w;
        if (si == 2)      w = (lane == i) ? 1.0f : 0.0f;
        else if (si == 0) w = 1.0f / 64.0f;
        else {
            const float neg = (1.0f - pos) * (1.0f / 63.0f);
            w = (lane == i) ? pos : neg;
        }
        const float dotv = wave_reduce_sum(w * x);
        if (lane == 0) atomicAdd(out, (m + lse - dotv) * (1.0f / 64.0f));
    }
}

extern "C" void kernel_launch(void* const* d_in, const int* in_sizes, int n_in,
                              void* d_out, int out_size, void* d_ws, size_t ws_size,
                              hipStream_t stream) {
    const float* fpv_slow   = (const float*)d_in[0];
    const float* fpv_fast   = (const float*)d_in[1];
    const float* tpv_slow   = (const float*)d_in[2];
    const float* tpv_fast   = (const float*)d_in[3];
    const float* labels_v    = (const float*)d_in[4];
    const float* labels_n    = (const float*)d_in[5];
    const float* labels_v_lt = (const float*)d_in[6];
    const float* labels_n_lt = (const float*)d_in[7];
    const int*   same_idx    = (const int*)d_in[8];
    const float* W_fpv = (const float*)d_in[9];
    const float* b_fpv = (const float*)d_in[10];
    const float* W_tpv = (const float*)d_in[11];
    const float* b_tpv = (const float*)d_in[12];

    float* pool = (float*)d_ws;                  // 2*64*2304 = 294912 floats
    float* gp   = pool + 2 * 64 * 2304;          // 1152*256  = 294912 floats
    float* ft   = gp + 1152 * 256;               // 2*64*256  = 32768 floats
    float* out  = (float*)d_out;

    hipMemsetAsync(d_out, 0, sizeof(float) * out_size, stream);

    pool_kernel<<<24576, 256, 0, stream>>>(fpv_slow, fpv_fast, tpv_slow, tpv_fast, pool);
    gemv_kernel<<<1152, 256, 0, stream>>>(pool, W_fpv, W_tpv, gp);
    finalize_kernel<<<128, 256, 0, stream>>>(pool, gp, b_fpv, b_tpv, ft);
    loss_kernel<<<64, 256, 0, stream>>>(ft, labels_v, labels_v_lt, labels_n, labels_n_lt,
                                        same_idx, out);
}